// Round 1
// baseline (711.851 us; speedup 1.0000x reference)
//
#include <hip/hip_runtime.h>

static constexpr int B_ = 2048;
static constexpr int T_ = 2048;
static constexpr int I_ = 9;
static constexpr int H_ = 16;

__device__ __forceinline__ float f_exp2(float x) {
#if __has_builtin(__builtin_amdgcn_exp2f)
  return __builtin_amdgcn_exp2f(x);
#else
  float r; asm volatile("v_exp_f32 %0, %1" : "=v"(r) : "v"(x)); return r;
#endif
}
__device__ __forceinline__ float f_rcp(float x) {
#if __has_builtin(__builtin_amdgcn_rcpf)
  return __builtin_amdgcn_rcpf(x);
#else
  float r; asm volatile("v_rcp_f32 %0, %1" : "=v"(r) : "v"(x)); return r;
#endif
}

// broadcast float from lane `lane` (uniform) across the wave via v_readlane
__device__ __forceinline__ float rlane(float v, int lane) {
  return __builtin_bit_cast(float,
      __builtin_amdgcn_readlane(__builtin_bit_cast(int, v), lane));
}

// DPP quad_perm broadcast: every lane gets the value of lane (l & ~3) + SEL
template <int SEL>
__device__ __forceinline__ float quad_bcast(float v) {
  constexpr int ctrl = SEL * 0x55;  // quad_perm:[SEL,SEL,SEL,SEL]
  return __builtin_bit_cast(float, __builtin_amdgcn_update_dpp(
      0, __builtin_bit_cast(int, v), ctrl, 0xF, 0xF, true));
}

__global__ __launch_bounds__(256) void ParityLSTM_kernel(
    const float* __restrict__ x, const int* __restrict__ x_lens,
    const float* __restrict__ W_ih, const float* __restrict__ W_hh,
    const float* __restrict__ b_ih, const float* __restrict__ b_hh,
    const float* __restrict__ W_lin, const float* __restrict__ b_lin,
    float* __restrict__ out) {
  const int lane = threadIdx.x & 63;
  const int wave = threadIdx.x >> 6;
  const int b = blockIdx.x * 4 + wave;  // one batch element per wave

  // interleaved gate layout: lane = (m << 2) | q
  // q: 0=i, 1=f, 2=g(tanh), 3=o ; m = cell index
  const int q = lane & 3;
  const int m = lane >> 2;
  const int g_id = q * H_ + m;  // row index in W_ih / W_hh / biases

  // per-lane weights (held in VGPRs for the whole kernel)
  float whh[H_];
#pragma unroll
  for (int k = 0; k < H_; ++k) whh[k] = W_hh[g_id * H_ + k];
  float wih[I_];
#pragma unroll
  for (int k = 0; k < I_; ++k) wih[k] = W_ih[g_id * I_ + k];
  const float bias = b_ih[g_id] + b_hh[g_id];

  // branchless sigmoid/tanh: act = m2 / (1 + exp2(a * sc1)) + a2
  const bool isG = (q == 2);
  const float sc1 = isG ? -2.8853900817779268f : -1.4426950408889634f;
  const float m2 = isG ? 2.0f : 1.0f;
  const float a2 = isG ? -1.0f : 0.0f;

  const int len = __builtin_amdgcn_readfirstlane(x_lens[b]);

  float c = 0.0f, h = 0.0f;
  const float* xb = x + (size_t)b * T_ * I_;

  // register-stage 64 timesteps: lane tt holds x[t0+tt][0..8]
  float xr[I_];
  {
    const float* xp = xb + (size_t)lane * I_;
#pragma unroll
    for (int k = 0; k < I_; ++k) xr[k] = xp[k];
  }

  for (int t0 = 0; t0 < len; t0 += 64) {
    // prefetch next chunk (hidden under the 64 inner steps)
    float xn[I_];
    const bool more = (t0 + 64) < len;
    if (more) {
      const float* xp = xb + (size_t)(t0 + 64 + lane) * I_;
#pragma unroll
      for (int k = 0; k < I_; ++k) xn[k] = xp[k];
    }
    const int ns = min(64, len - t0);
    for (int s = 0; s < ns; ++s) {
      // gate pre-activation: bias + x_t @ W_ih[g]  +  h @ W_hh[g]
      float acc[4] = {bias, 0.0f, 0.0f, 0.0f};
#pragma unroll
      for (int k = 0; k < I_; ++k)
        acc[k & 3] = fmaf(rlane(xr[k], s), wih[k], acc[k & 3]);
#pragma unroll
      for (int k = 0; k < H_; ++k)  // h[k] lives (replicated) at lane 4k
        acc[k & 3] = fmaf(rlane(h, 4 * k), whh[k], acc[k & 3]);
      const float a = (acc[0] + acc[1]) + (acc[2] + acc[3]);

      // activation (sigmoid for i,f,o; tanh for g) — branchless
      const float e = f_exp2(a * sc1);
      const float r = f_rcp(1.0f + e);
      const float act = fmaf(m2, r, a2);

      // redistribute i,f,g,o within the quad via DPP (VALU speed)
      const float iv = quad_bcast<0>(act);
      const float fv = quad_bcast<1>(act);
      const float gv = quad_bcast<2>(act);
      const float ov = quad_bcast<3>(act);

      c = fmaf(fv, c, iv * gv);
      const float e2 = f_exp2(c * -2.8853900817779268f);
      const float th = fmaf(2.0f, f_rcp(1.0f + e2), -1.0f);
      h = ov * th;
    }
#pragma unroll
    for (int k = 0; k < I_; ++k) xr[k] = xn[k];
  }

  // epilogue: out[b][j] = sum_m h[m] * W_lin[j][m] + b_lin[j]
  const float wl = (q < 2) ? W_lin[q * H_ + m] : 0.0f;
  float p = h * wl;
  p += __shfl_xor(p, 4, 64);
  p += __shfl_xor(p, 8, 64);
  p += __shfl_xor(p, 16, 64);
  p += __shfl_xor(p, 32, 64);  // now lanes with same q hold the q-group sum
  if (lane < 2) out[2 * b + lane] = p + b_lin[lane];
}

extern "C" void kernel_launch(void* const* d_in, const int* in_sizes, int n_in,
                              void* d_out, int out_size, void* d_ws,
                              size_t ws_size, hipStream_t stream) {
  const float* x = (const float*)d_in[0];
  const int* x_lens = (const int*)d_in[1];
  const float* W_ih = (const float*)d_in[2];
  const float* W_hh = (const float*)d_in[3];
  const float* b_ih = (const float*)d_in[4];
  const float* b_hh = (const float*)d_in[5];
  const float* W_lin = (const float*)d_in[6];
  const float* b_lin = (const float*)d_in[7];
  float* out = (float*)d_out;

  dim3 grid(B_ / 4);   // 512 blocks
  dim3 block(256);     // 4 waves/block, 1 batch element per wave
  ParityLSTM_kernel<<<grid, block, 0, stream>>>(x, x_lens, W_ih, W_hh, b_ih,
                                                b_hh, W_lin, b_lin, out);
}

// Round 2
// 683.263 us; speedup vs baseline: 1.0418x; 1.0418x over previous
//
#include <hip/hip_runtime.h>

static constexpr int B_ = 2048;
static constexpr int T_ = 2048;
static constexpr int I_ = 9;
static constexpr int H_ = 16;

__device__ __forceinline__ float f_exp2(float x) {
#if __has_builtin(__builtin_amdgcn_exp2f)
  return __builtin_amdgcn_exp2f(x);
#else
  float r; asm volatile("v_exp_f32 %0, %1" : "=v"(r) : "v"(x)); return r;
#endif
}
__device__ __forceinline__ float f_rcp(float x) {
#if __has_builtin(__builtin_amdgcn_rcpf)
  return __builtin_amdgcn_rcpf(x);
#else
  float r; asm volatile("v_rcp_f32 %0, %1" : "=v"(r) : "v"(x)); return r;
#endif
}

// broadcast float from lane `lane` (wave-uniform index) via v_readlane
__device__ __forceinline__ float rlane(float v, int lane) {
  return __builtin_bit_cast(float,
      __builtin_amdgcn_readlane(__builtin_bit_cast(int, v), lane));
}

// DPP quad_perm broadcast: every lane gets the value of lane (l & ~3) + SEL
template <int SEL>
__device__ __forceinline__ float quad_bcast(float v) {
  constexpr int ctrl = SEL * 0x55;  // quad_perm:[SEL,SEL,SEL,SEL]
  return __builtin_bit_cast(float, __builtin_amdgcn_update_dpp(
      0, __builtin_bit_cast(int, v), ctrl, 0xF, 0xF, true));
}

__global__ __launch_bounds__(256, 1) void ParityLSTM_kernel(
    const float* __restrict__ x, const int* __restrict__ x_lens,
    const float* __restrict__ W_ih, const float* __restrict__ W_hh,
    const float* __restrict__ b_ih, const float* __restrict__ b_hh,
    const float* __restrict__ W_lin, const float* __restrict__ b_lin,
    float* __restrict__ out) {
  const int lane = threadIdx.x & 63;
  const int wave = threadIdx.x >> 6;
  const int b = blockIdx.x * 4 + wave;  // one batch element per wave

  // interleaved gate layout: lane = (m << 2) | q
  // q: 0=i, 1=f, 2=g(tanh), 3=o ; m = cell index
  const int q = lane & 3;
  const int m = lane >> 2;
  const int g_id = q * H_ + m;  // row index in W_ih / W_hh / biases

  // activation constants; k = -2/ln2 for the tanh lane
  const bool isG = (q == 2);
  constexpr float kT = -2.8853900817779268f;  // -2/ln2
  constexpr float kS = -1.4426950408889634f;  // -1/ln2
  const float sc1 = isG ? kT : kS;
  // g lane outputs k*tanh(raw) so c is maintained in the kT-scaled domain:
  // act = m2 * rcp(1 + exp2(a_scaled)) + a2
  const float m2 = isG ? (2.0f * kT) : 1.0f;
  const float a2 = isG ? (-kT) : 0.0f;

  // per-lane weights, PRE-SCALED by sc1 (folds the activation input scale)
  float whh[H_];
#pragma unroll
  for (int k = 0; k < H_; ++k) whh[k] = W_hh[g_id * H_ + k] * sc1;
  float wih[I_];
#pragma unroll
  for (int k = 0; k < I_; ++k) wih[k] = W_ih[g_id * I_ + k] * sc1;
  const float bias = (b_ih[g_id] + b_hh[g_id]) * sc1;

  const int len = __builtin_amdgcn_readfirstlane(x_lens[b]);

  float cs = 0.0f, h = 0.0f;  // cs = kT * c (scaled cell state)
  const float* xb = x + (size_t)b * T_ * I_;

  // register-stage 64 timesteps: lane tt holds x[t0+tt][0..8]
  float xr[I_];
  {
    const float* xp = xb + (size_t)lane * I_;
#pragma unroll
    for (int k = 0; k < I_; ++k) xr[k] = xp[k];
  }

  for (int t0 = 0; t0 < len; t0 += 64) {
    // prefetch next chunk (hidden under the 64 inner steps)
    float xn[I_];
    const bool more = (t0 + 64) < len;
    if (more) {
      const float* xp = xb + (size_t)(t0 + 64 + lane) * I_;
#pragma unroll
      for (int k = 0; k < I_; ++k) xn[k] = xp[k];
    }
    const int ns = min(64, len - t0);
#pragma unroll 4
    for (int s = 0; s < ns; ++s) {
      // gate pre-activation (scaled): bias' + x_t@wih' + h@whh'
      float acc[4] = {bias, 0.0f, 0.0f, 0.0f};
#pragma unroll
      for (int k = 0; k < I_; ++k)
        acc[k & 3] = fmaf(rlane(xr[k], s), wih[k], acc[k & 3]);
#pragma unroll
      for (int k = 0; k < H_; ++k)  // h[k] lives (replicated) at lane 4k
        acc[k & 3] = fmaf(rlane(h, 4 * k), whh[k], acc[k & 3]);
      const float a = (acc[0] + acc[1]) + (acc[2] + acc[3]);

      // activation: sigmoid for i,f,o ; kT*tanh for g — branchless, no
      // dependent pre-multiply (scale folded into weights)
      const float e = f_exp2(a);
      const float r = f_rcp(1.0f + e);
      const float act = fmaf(m2, r, a2);

      // redistribute within the quad via DPP; iv,gv first (needed first)
      const float iv = quad_bcast<0>(act);
      const float gv = quad_bcast<2>(act);  // = kT * g
      const float fv = quad_bcast<1>(act);
      const float ov = quad_bcast<3>(act);

      cs = fmaf(fv, cs, iv * gv);           // cs stays kT-scaled
      const float e2 = f_exp2(cs);          // = exp(-2c)
      const float th = fmaf(2.0f, f_rcp(1.0f + e2), -1.0f);  // tanh(c)
      h = ov * th;
    }
    if (more) {
#pragma unroll
      for (int k = 0; k < I_; ++k) xr[k] = xn[k];
    }
  }

  // epilogue: out[b][j] = sum_m h[m] * W_lin[j][m] + b_lin[j]
  const float wl = (q < 2) ? W_lin[q * H_ + m] : 0.0f;
  float p = h * wl;
  p += __shfl_xor(p, 4, 64);
  p += __shfl_xor(p, 8, 64);
  p += __shfl_xor(p, 16, 64);
  p += __shfl_xor(p, 32, 64);  // lanes with same q now hold the q-group sum
  if (lane < 2) out[2 * b + lane] = p + b_lin[lane];
}

extern "C" void kernel_launch(void* const* d_in, const int* in_sizes, int n_in,
                              void* d_out, int out_size, void* d_ws,
                              size_t ws_size, hipStream_t stream) {
  const float* x = (const float*)d_in[0];
  const int* x_lens = (const int*)d_in[1];
  const float* W_ih = (const float*)d_in[2];
  const float* W_hh = (const float*)d_in[3];
  const float* b_ih = (const float*)d_in[4];
  const float* b_hh = (const float*)d_in[5];
  const float* W_lin = (const float*)d_in[6];
  const float* b_lin = (const float*)d_in[7];
  float* out = (float*)d_out;

  dim3 grid(B_ / 4);   // 512 blocks
  dim3 block(256);     // 4 waves/block, 1 batch element per wave
  ParityLSTM_kernel<<<grid, block, 0, stream>>>(x, x_lens, W_ih, W_hh, b_ih,
                                                b_hh, W_lin, b_lin, out);
}